// Round 3
// baseline (313.218 us; speedup 1.0000x reference)
//
#include <hip/hip_runtime.h>

// Problem constants (from reference)
#define COLS    2048
#define CPC     32          // cells per column == 32 bits -> one word per column
#define NCELLS  65536       // COLS * CPC
#define SEGS    16
#define SYN     32
#define THRESH  13

#define CELLS_PER_BLOCK 16  // 4 waves x 4 cells each
#define PREDICT_GRID (NCELLS / CELLS_PER_BLOCK)   // 4096 blocks

// ---------------------------------------------------------------------------
// Kernel 1: active-cell phase (unchanged — correct and tiny).
// ---------------------------------------------------------------------------
__global__ __launch_bounds__(256) void tm_active_kernel(
    const float* __restrict__ active_columns,
    const float* __restrict__ prev_predictive,
    float* __restrict__ out_active,
    unsigned int* __restrict__ ws_mask,
    int* __restrict__ ws_cnt)
{
    int n = blockIdx.x * 256 + threadIdx.x;   // cell index, grid is exact
    int c = n >> 5;                            // column
    int j = n & 31;                            // cell within column
    int lane = threadIdx.x & 63;

    bool predbit    = prev_predictive[n] > 0.0f;
    bool col_active = active_columns[c] > 0.0f;

    unsigned long long pb = __ballot(predbit);
    unsigned int colmask = (lane < 32) ? (unsigned int)pb : (unsigned int)(pb >> 32);
    bool has_pred = (colmask != 0u);

    bool active = col_active && (has_pred ? predbit : true);
    out_active[n] = active ? 1.0f : 0.0f;

    unsigned long long ab = __ballot(active);
    if (lane == 0)  ws_mask[c] = (unsigned int)ab;
    if (lane == 32) ws_mask[c] = (unsigned int)(ab >> 32);

    bool rep = (j == 0);
    unsigned long long aa = __ballot(rep && col_active);
    unsigned long long pp = __ballot(rep && col_active && has_pred);
    if (lane == 0) {
        atomicAdd(&ws_cnt[0], __popcll(aa));
        atomicAdd(&ws_cnt[1], __popcll(pp));
    }
}

// ---------------------------------------------------------------------------
// Kernel 2: predictive phase.
//
// R2 lesson: the compiler register-minimized the load/use sequence down to
// VGPR_Count=16, serializing loads (~1 in flight/wave) -> latency-bound at
// 2.6 TB/s effective. R3: each wave owns 4 consecutive cells and issues ALL
// 16 coalesced 1KB vector loads (16 KB/wave) into explicit register arrays
// BEFORE any consumption; __launch_bounds__(256,2) raises the VGPR cap to
// 256 so the allocator can keep them live. 8 waves/CU x 16 KB = 128 KB in
// flight per CU >> the ~9 KB Little's-law requirement at HBM rate.
//
// Per-cell reduction (unchanged): lane i's int4 element e belongs to segment
// e/8; pack the two per-lane partials, butterfly-ADD over the 8-lane group,
// unpack+max, butterfly-MAX across groups, lane 0 writes.
// ---------------------------------------------------------------------------
__global__ __launch_bounds__(256, 2) void tm_predict_kernel(
    const int*   __restrict__ seg_pre,
    const float* __restrict__ seg_perm,
    const unsigned int* __restrict__ ws_mask,
    const int*   __restrict__ ws_cnt,
    float* __restrict__ out_pred,
    float* __restrict__ out_anomaly)
{
    __shared__ unsigned int mask[COLS];   // 8 KB active bitmask
    int tid = threadIdx.x;
    #pragma unroll
    for (int i = 0; i < COLS / 256; ++i)
        mask[tid + 256 * i] = ws_mask[tid + 256 * i];
    __syncthreads();

    int wave = tid >> 6;
    int lane = tid & 63;
    int cell0 = blockIdx.x * CELLS_PER_BLOCK + wave * 4;   // this wave's 4 cells

    const int4*   pre4  = (const int4*)  seg_pre  + (size_t)cell0 * 128;
    const float4* perm4 = (const float4*)seg_perm + (size_t)cell0 * 128;

    // ---- Phase A: issue all 16 loads (no consumption yet) ----
    int4   P[8];
    float4 Q[8];
    #pragma unroll
    for (int c = 0; c < 4; ++c) {
        P[2 * c]     = pre4 [c * 128 + lane];
        P[2 * c + 1] = pre4 [c * 128 + lane + 64];
        Q[2 * c]     = perm4[c * 128 + lane];
        Q[2 * c + 1] = perm4[c * 128 + lane + 64];
    }

    // ---- Phase B: per-cell count + reduce ----
    #pragma unroll
    for (int c = 0; c < 4; ++c) {
        int4   p0 = P[2 * c],     p1 = P[2 * c + 1];
        float4 q0 = Q[2 * c],     q1 = Q[2 * c + 1];

        int c0 = 0, c1 = 0;
        c0 += (q0.x >= 0.5f && ((mask[(unsigned)p0.x >> 5] >> ((unsigned)p0.x & 31u)) & 1u)) ? 1 : 0;
        c0 += (q0.y >= 0.5f && ((mask[(unsigned)p0.y >> 5] >> ((unsigned)p0.y & 31u)) & 1u)) ? 1 : 0;
        c0 += (q0.z >= 0.5f && ((mask[(unsigned)p0.z >> 5] >> ((unsigned)p0.z & 31u)) & 1u)) ? 1 : 0;
        c0 += (q0.w >= 0.5f && ((mask[(unsigned)p0.w >> 5] >> ((unsigned)p0.w & 31u)) & 1u)) ? 1 : 0;
        c1 += (q1.x >= 0.5f && ((mask[(unsigned)p1.x >> 5] >> ((unsigned)p1.x & 31u)) & 1u)) ? 1 : 0;
        c1 += (q1.y >= 0.5f && ((mask[(unsigned)p1.y >> 5] >> ((unsigned)p1.y & 31u)) & 1u)) ? 1 : 0;
        c1 += (q1.z >= 0.5f && ((mask[(unsigned)p1.z >> 5] >> ((unsigned)p1.z & 31u)) & 1u)) ? 1 : 0;
        c1 += (q1.w >= 0.5f && ((mask[(unsigned)p1.w >> 5] >> ((unsigned)p1.w & 31u)) & 1u)) ? 1 : 0;

        int v = c0 | (c1 << 16);
        v += __shfl_xor(v, 1, 64);
        v += __shfl_xor(v, 2, 64);
        v += __shfl_xor(v, 4, 64);
        int m = max(v & 0xffff, v >> 16);
        m = max(m, __shfl_xor(m, 8, 64));
        m = max(m, __shfl_xor(m, 16, 64));
        m = max(m, __shfl_xor(m, 32, 64));

        if (lane == 0)
            out_pred[cell0 + c] = (m >= THRESH) ? 1.0f : 0.0f;
    }

    // anomaly (kernel 1's atomics are visible across the kernel boundary)
    if (blockIdx.x == 0 && tid == 0) {
        int na = ws_cnt[0];
        int np = ws_cnt[1];
        *out_anomaly = 1.0f - (float)np / (float)(na > 1 ? na : 1);
    }
}

// ---------------------------------------------------------------------------
// Inputs (setup_inputs order):
//   d_in[0] active_columns  f32 [2048]
//   d_in[1] prev_active     f32 [65536]   (unused by the reference)
//   d_in[2] prev_predictive f32 [65536]
//   d_in[3] seg_pre         i32 [65536*16*32]
//   d_in[4] seg_perm        f32 [65536*16*32]
// Output: f32 [65536 active | 65536 predictive | 1 anomaly]
// Workspace: ws[0..2047] u32 bitmask, ws[2048..2049] i32 counters
// ---------------------------------------------------------------------------
extern "C" void kernel_launch(void* const* d_in, const int* in_sizes, int n_in,
                              void* d_out, int out_size, void* d_ws, size_t ws_size,
                              hipStream_t stream) {
    const float* active_columns  = (const float*)d_in[0];
    const float* prev_predictive = (const float*)d_in[2];
    const int*   seg_pre         = (const int*)d_in[3];
    const float* seg_perm        = (const float*)d_in[4];
    float* out = (float*)d_out;

    unsigned int* ws_mask = (unsigned int*)d_ws;
    int* ws_cnt = (int*)((char*)d_ws + COLS * sizeof(unsigned int));

    hipMemsetAsync(ws_cnt, 0, 2 * sizeof(int), stream);

    tm_active_kernel<<<NCELLS / 256, 256, 0, stream>>>(
        active_columns, prev_predictive, out, ws_mask, ws_cnt);

    tm_predict_kernel<<<PREDICT_GRID, 256, 0, stream>>>(
        seg_pre, seg_perm, ws_mask, ws_cnt,
        out + NCELLS, out + 2 * NCELLS);
}

// Round 4
// 285.999 us; speedup vs baseline: 1.0952x; 1.0952x over previous
//
#include <hip/hip_runtime.h>

// Problem constants (from reference)
#define COLS    2048
#define CPC     32          // cells per column == 32 bits -> one word per column
#define NCELLS  65536       // COLS * CPC
#define SEGS    16
#define SYN     32
#define THRESH  13

#define CELLS_PER_BLOCK 16  // 4 waves x 4 cells each
#define PREDICT_GRID (NCELLS / CELLS_PER_BLOCK)   // 4096 blocks

// ---------------------------------------------------------------------------
// Kernel 1: active-cell phase. No atomics (R3 lesson: 2048 same-address
// device atomics are a serialization hazard). Per-column anomaly inputs are
// written as independent flag bytes; tm_predict block 0 reduces them.
// ---------------------------------------------------------------------------
__global__ __launch_bounds__(256) void tm_active_kernel(
    const float* __restrict__ active_columns,
    const float* __restrict__ prev_predictive,
    float* __restrict__ out_active,
    unsigned int* __restrict__ ws_mask,
    unsigned char* __restrict__ ws_flags)
{
    int n = blockIdx.x * 256 + threadIdx.x;   // cell index, grid is exact
    int c = n >> 5;                            // column
    int j = n & 31;                            // cell within column
    int lane = threadIdx.x & 63;

    bool predbit    = prev_predictive[n] > 0.0f;
    bool col_active = active_columns[c] > 0.0f;

    unsigned long long pb = __ballot(predbit);
    unsigned int colmask = (lane < 32) ? (unsigned int)pb : (unsigned int)(pb >> 32);
    bool has_pred = (colmask != 0u);

    bool active = col_active && (has_pred ? predbit : true);
    out_active[n] = active ? 1.0f : 0.0f;

    unsigned long long ab = __ballot(active);
    if (lane == 0)  ws_mask[c] = (unsigned int)ab;
    if (lane == 32) ws_mask[c] = (unsigned int)(ab >> 32);

    // One flag byte per column, written contention-free by lanes 0 and 32.
    if (j == 0)
        ws_flags[c] = (unsigned char)((col_active ? 1 : 0) |
                                      ((col_active && has_pred) ? 2 : 0));
}

// ---------------------------------------------------------------------------
// Kernel 2: predictive phase.
//
// R3 lesson: the compiler SANK the batched loads back into the consume loop
// (VGPR_Count=40 -> ~2 loads in flight -> latency-bound at 2.6 TB/s).
// R4: __builtin_amdgcn_sched_barrier(0) between load-issue and consumption
// is a hard fence the scheduler cannot move memory ops across, so all 16
// coalesced 1 KB loads (16 KB/wave, 256 cache lines) are genuinely
// outstanding before the first s_waitcnt.
//
// Per-cell reduction: lane i's int4 element e belongs to segment e/8; pack
// the two per-lane partials, butterfly-ADD over the 8-lane group, unpack+max,
// butterfly-MAX across groups, lane 0 writes.
// ---------------------------------------------------------------------------
__global__ __launch_bounds__(256) void tm_predict_kernel(
    const int*   __restrict__ seg_pre,
    const float* __restrict__ seg_perm,
    const unsigned int* __restrict__ ws_mask,
    const unsigned char* __restrict__ ws_flags,
    float* __restrict__ out_pred,
    float* __restrict__ out_anomaly)
{
    __shared__ unsigned int mask[COLS];   // 8 KB active bitmask
    __shared__ int red[4];                // block-0 anomaly reduction scratch
    int tid = threadIdx.x;
    #pragma unroll
    for (int i = 0; i < COLS / 256; ++i)
        mask[tid + 256 * i] = ws_mask[tid + 256 * i];
    __syncthreads();

    int wave = tid >> 6;
    int lane = tid & 63;
    int cell0 = blockIdx.x * CELLS_PER_BLOCK + wave * 4;   // this wave's 4 cells

    const int4*   pre4  = (const int4*)  seg_pre  + (size_t)cell0 * 128;
    const float4* perm4 = (const float4*)seg_perm + (size_t)cell0 * 128;

    // ---- Phase A: issue all 16 loads ----
    int4   P[8];
    float4 Q[8];
    #pragma unroll
    for (int c = 0; c < 4; ++c) {
        P[2 * c]     = pre4 [c * 128 + lane];
        P[2 * c + 1] = pre4 [c * 128 + lane + 64];
        Q[2 * c]     = perm4[c * 128 + lane];
        Q[2 * c + 1] = perm4[c * 128 + lane + 64];
    }
    // Hard scheduling fence: nothing (incl. these loads) may cross.
    __builtin_amdgcn_sched_barrier(0);

    // ---- Phase B: per-cell count + reduce ----
    #pragma unroll
    for (int c = 0; c < 4; ++c) {
        int4   p0 = P[2 * c],     p1 = P[2 * c + 1];
        float4 q0 = Q[2 * c],     q1 = Q[2 * c + 1];

        int c0 = 0, c1 = 0;
        c0 += (q0.x >= 0.5f && ((mask[(unsigned)p0.x >> 5] >> ((unsigned)p0.x & 31u)) & 1u)) ? 1 : 0;
        c0 += (q0.y >= 0.5f && ((mask[(unsigned)p0.y >> 5] >> ((unsigned)p0.y & 31u)) & 1u)) ? 1 : 0;
        c0 += (q0.z >= 0.5f && ((mask[(unsigned)p0.z >> 5] >> ((unsigned)p0.z & 31u)) & 1u)) ? 1 : 0;
        c0 += (q0.w >= 0.5f && ((mask[(unsigned)p0.w >> 5] >> ((unsigned)p0.w & 31u)) & 1u)) ? 1 : 0;
        c1 += (q1.x >= 0.5f && ((mask[(unsigned)p1.x >> 5] >> ((unsigned)p1.x & 31u)) & 1u)) ? 1 : 0;
        c1 += (q1.y >= 0.5f && ((mask[(unsigned)p1.y >> 5] >> ((unsigned)p1.y & 31u)) & 1u)) ? 1 : 0;
        c1 += (q1.z >= 0.5f && ((mask[(unsigned)p1.z >> 5] >> ((unsigned)p1.z & 31u)) & 1u)) ? 1 : 0;
        c1 += (q1.w >= 0.5f && ((mask[(unsigned)p1.w >> 5] >> ((unsigned)p1.w & 31u)) & 1u)) ? 1 : 0;

        int v = c0 | (c1 << 16);
        v += __shfl_xor(v, 1, 64);
        v += __shfl_xor(v, 2, 64);
        v += __shfl_xor(v, 4, 64);
        int m = max(v & 0xffff, v >> 16);
        m = max(m, __shfl_xor(m, 8, 64));
        m = max(m, __shfl_xor(m, 16, 64));
        m = max(m, __shfl_xor(m, 32, 64));

        if (lane == 0)
            out_pred[cell0 + c] = (m >= THRESH) ? 1.0f : 0.0f;
    }

    // ---- Anomaly: block 0 reduces the 2048 per-column flag bytes ----
    if (blockIdx.x == 0) {
        int na = 0, np = 0;
        #pragma unroll
        for (int i = 0; i < COLS / 256; ++i) {
            unsigned f = ws_flags[tid * (COLS / 256) + i];
            na += (f & 1);
            np += ((f >> 1) & 1);
        }
        int v = na | (np << 16);
        v += __shfl_xor(v, 1, 64);
        v += __shfl_xor(v, 2, 64);
        v += __shfl_xor(v, 4, 64);
        v += __shfl_xor(v, 8, 64);
        v += __shfl_xor(v, 16, 64);
        v += __shfl_xor(v, 32, 64);
        if (lane == 0) red[wave] = v;
        __syncthreads();
        if (tid == 0) {
            int t = red[0] + red[1] + red[2] + red[3];
            int NA = t & 0xffff, NP = t >> 16;
            *out_anomaly = 1.0f - (float)NP / (float)(NA > 1 ? NA : 1);
        }
    }
}

// ---------------------------------------------------------------------------
// Inputs (setup_inputs order):
//   d_in[0] active_columns  f32 [2048]
//   d_in[1] prev_active     f32 [65536]   (unused by the reference)
//   d_in[2] prev_predictive f32 [65536]
//   d_in[3] seg_pre         i32 [65536*16*32]
//   d_in[4] seg_perm        f32 [65536*16*32]
// Output: f32 [65536 active | 65536 predictive | 1 anomaly]
// Workspace: ws[0..2047] u32 bitmask, then 2048 u8 column flags
// ---------------------------------------------------------------------------
extern "C" void kernel_launch(void* const* d_in, const int* in_sizes, int n_in,
                              void* d_out, int out_size, void* d_ws, size_t ws_size,
                              hipStream_t stream) {
    const float* active_columns  = (const float*)d_in[0];
    const float* prev_predictive = (const float*)d_in[2];
    const int*   seg_pre         = (const int*)d_in[3];
    const float* seg_perm        = (const float*)d_in[4];
    float* out = (float*)d_out;

    unsigned int*  ws_mask  = (unsigned int*)d_ws;
    unsigned char* ws_flags = (unsigned char*)d_ws + COLS * sizeof(unsigned int);

    tm_active_kernel<<<NCELLS / 256, 256, 0, stream>>>(
        active_columns, prev_predictive, out, ws_mask, ws_flags);

    tm_predict_kernel<<<PREDICT_GRID, 256, 0, stream>>>(
        seg_pre, seg_perm, ws_mask, ws_flags,
        out + NCELLS, out + 2 * NCELLS);
}

// Round 5
// 281.249 us; speedup vs baseline: 1.1137x; 1.0169x over previous
//
#include <hip/hip_runtime.h>

// Problem constants (from reference)
#define COLS    2048
#define CPC     32          // cells per column == 32 bits -> one word per column
#define NCELLS  65536       // COLS * CPC
#define SEGS    16
#define SYN     32
#define THRESH  13

#define CPB     8                      // cells per block (4 waves x 2 cells)
#define PREDICT_GRID (NCELLS / CPB)    // 8192 blocks

// ---------------------------------------------------------------------------
// Kernel 1: active-cell phase (unchanged — correct, tiny, atomic-free).
// ---------------------------------------------------------------------------
__global__ __launch_bounds__(256) void tm_active_kernel(
    const float* __restrict__ active_columns,
    const float* __restrict__ prev_predictive,
    float* __restrict__ out_active,
    unsigned int* __restrict__ ws_mask,
    unsigned char* __restrict__ ws_flags)
{
    int n = blockIdx.x * 256 + threadIdx.x;   // cell index, grid is exact
    int c = n >> 5;                            // column
    int j = n & 31;                            // cell within column
    int lane = threadIdx.x & 63;

    bool predbit    = prev_predictive[n] > 0.0f;
    bool col_active = active_columns[c] > 0.0f;

    unsigned long long pb = __ballot(predbit);
    unsigned int colmask = (lane < 32) ? (unsigned int)pb : (unsigned int)(pb >> 32);
    bool has_pred = (colmask != 0u);

    bool active = col_active && (has_pred ? predbit : true);
    out_active[n] = active ? 1.0f : 0.0f;

    unsigned long long ab = __ballot(active);
    if (lane == 0)  ws_mask[c] = (unsigned int)ab;
    if (lane == 32) ws_mask[c] = (unsigned int)(ab >> 32);

    if (j == 0)
        ws_flags[c] = (unsigned char)((col_active ? 1 : 0) |
                                      ((col_active && has_pred) ? 2 : 0));
}

// ---------------------------------------------------------------------------
// Async global->LDS DMA, 1 KB per wave-instruction: lane i's 16 B from
// g + i*16 lands at lds + i*16 (wave-uniform LDS base + lane*size — m104).
// Fire-and-forget: no result VGPRs, so the compiler cannot serialize it the
// way it serialized register-held loads in R2-R4 (the 104 us plateau).
// ---------------------------------------------------------------------------
typedef const __attribute__((address_space(1))) void* gas_ptr;
typedef __attribute__((address_space(3)))       void* las_ptr;

__device__ __forceinline__ void dma_1kb(const char* g, char* lds, int lane) {
    __builtin_amdgcn_global_load_lds((gas_ptr)(g + lane * 16), (las_ptr)lds, 16, 0, 0);
}

// ---------------------------------------------------------------------------
// Kernel 2: predictive phase via LDS DMA staging.
//
// Each wave owns 2 cells and DMAs their pre+perm data (8 x 1 KB) into LDS
// back-to-back — 8 KB outstanding per wave, 128 KB (2048 lines) per CU at
// 4 blocks/CU, vs the ~60-line ceiling the register path achieved. Waves
// only consume data they themselves staged, so the single __syncthreads
// (which drains vmcnt(0) before s_barrier) is the only wait in the kernel.
//
// Per-cell reduction (verified since R2): lane i handles int4 elements i
// and i+64 of the cell's 128; element e belongs to segment e/8. Pack the two
// per-lane partials, butterfly-ADD over the 8-lane group, unpack+max,
// butterfly-MAX across groups, lane 0 writes.
// LDS = 8192 (mask) + 16384 (pre) + 16384 (perm) = 40960 B -> exactly
// 4 blocks/CU of the 160 KiB.
// ---------------------------------------------------------------------------
__global__ __launch_bounds__(256) void tm_predict_kernel(
    const int*   __restrict__ seg_pre,
    const float* __restrict__ seg_perm,
    const unsigned int* __restrict__ ws_mask,
    const unsigned char* __restrict__ ws_flags,
    float* __restrict__ out_pred,
    float* __restrict__ out_anomaly)
{
    __shared__ unsigned int mask[COLS];       // 8 KB active bitmask
    __shared__ char pre_lds [CPB * 2048];     // 16 KB: 8 cells x 512 i32
    __shared__ char perm_lds[CPB * 2048];     // 16 KB: 8 cells x 512 f32

    int tid  = threadIdx.x;
    int wave = tid >> 6;
    int lane = tid & 63;
    int cell0 = blockIdx.x * CPB;

    // ---- Issue this wave's 8 DMAs first (they fly during mask staging) ----
    #pragma unroll
    for (int k = 0; k < 2; ++k) {
        int c = 2 * wave + k;
        const char* gp = (const char*)(seg_pre  + (size_t)(cell0 + c) * 512);
        const char* gq = (const char*)(seg_perm + (size_t)(cell0 + c) * 512);
        dma_1kb(gp,        pre_lds  + c * 2048,        lane);
        dma_1kb(gp + 1024, pre_lds  + c * 2048 + 1024, lane);
        dma_1kb(gq,        perm_lds + c * 2048,        lane);
        dma_1kb(gq + 1024, perm_lds + c * 2048 + 1024, lane);
    }

    // ---- Stage the 8 KB mask while the DMAs are in flight ----
    #pragma unroll
    for (int i = 0; i < 2; ++i)
        ((uint4*)mask)[tid + 256 * i] = ((const uint4*)ws_mask)[tid + 256 * i];

    __syncthreads();   // s_waitcnt vmcnt(0) lgkmcnt(0) + s_barrier: all LDS ready

    // ---- Consume: 2 cells per wave, zero further memory waits ----
    #pragma unroll
    for (int k = 0; k < 2; ++k) {
        int c = 2 * wave + k;
        const int4*   pl = (const int4*)  (pre_lds  + c * 2048);
        const float4* ql = (const float4*)(perm_lds + c * 2048);

        int4   p0 = pl[lane], p1 = pl[lane + 64];
        float4 q0 = ql[lane], q1 = ql[lane + 64];

        int c0 = 0, c1 = 0;
        c0 += (q0.x >= 0.5f && ((mask[(unsigned)p0.x >> 5] >> ((unsigned)p0.x & 31u)) & 1u)) ? 1 : 0;
        c0 += (q0.y >= 0.5f && ((mask[(unsigned)p0.y >> 5] >> ((unsigned)p0.y & 31u)) & 1u)) ? 1 : 0;
        c0 += (q0.z >= 0.5f && ((mask[(unsigned)p0.z >> 5] >> ((unsigned)p0.z & 31u)) & 1u)) ? 1 : 0;
        c0 += (q0.w >= 0.5f && ((mask[(unsigned)p0.w >> 5] >> ((unsigned)p0.w & 31u)) & 1u)) ? 1 : 0;
        c1 += (q1.x >= 0.5f && ((mask[(unsigned)p1.x >> 5] >> ((unsigned)p1.x & 31u)) & 1u)) ? 1 : 0;
        c1 += (q1.y >= 0.5f && ((mask[(unsigned)p1.y >> 5] >> ((unsigned)p1.y & 31u)) & 1u)) ? 1 : 0;
        c1 += (q1.z >= 0.5f && ((mask[(unsigned)p1.z >> 5] >> ((unsigned)p1.z & 31u)) & 1u)) ? 1 : 0;
        c1 += (q1.w >= 0.5f && ((mask[(unsigned)p1.w >> 5] >> ((unsigned)p1.w & 31u)) & 1u)) ? 1 : 0;

        int v = c0 | (c1 << 16);
        v += __shfl_xor(v, 1, 64);
        v += __shfl_xor(v, 2, 64);
        v += __shfl_xor(v, 4, 64);
        int m = max(v & 0xffff, v >> 16);
        m = max(m, __shfl_xor(m, 8, 64));
        m = max(m, __shfl_xor(m, 16, 64));
        m = max(m, __shfl_xor(m, 32, 64));

        if (lane == 0)
            out_pred[cell0 + c] = (m >= THRESH) ? 1.0f : 0.0f;
    }

    // ---- Anomaly: block 0 / wave 0 reduces 2048 flag bytes (no LDS) ----
    if (blockIdx.x == 0 && tid < 64) {
        const unsigned int* f = (const unsigned int*)ws_flags;
        int na = 0, np = 0;
        #pragma unroll
        for (int i = 0; i < 8; ++i) {
            unsigned w = f[tid * 8 + i];
            na += __popc(w & 0x01010101u);
            np += __popc(w & 0x02020202u);
        }
        int v = na | (np << 16);
        v += __shfl_xor(v, 1, 64);
        v += __shfl_xor(v, 2, 64);
        v += __shfl_xor(v, 4, 64);
        v += __shfl_xor(v, 8, 64);
        v += __shfl_xor(v, 16, 64);
        v += __shfl_xor(v, 32, 64);
        if (tid == 0) {
            int NA = v & 0xffff, NP = v >> 16;
            *out_anomaly = 1.0f - (float)NP / (float)(NA > 1 ? NA : 1);
        }
    }
}

// ---------------------------------------------------------------------------
// Inputs (setup_inputs order):
//   d_in[0] active_columns  f32 [2048]
//   d_in[1] prev_active     f32 [65536]   (unused by the reference)
//   d_in[2] prev_predictive f32 [65536]
//   d_in[3] seg_pre         i32 [65536*16*32]
//   d_in[4] seg_perm        f32 [65536*16*32]
// Output: f32 [65536 active | 65536 predictive | 1 anomaly]
// Workspace: ws[0..2047] u32 bitmask, then 2048 u8 column flags
// ---------------------------------------------------------------------------
extern "C" void kernel_launch(void* const* d_in, const int* in_sizes, int n_in,
                              void* d_out, int out_size, void* d_ws, size_t ws_size,
                              hipStream_t stream) {
    const float* active_columns  = (const float*)d_in[0];
    const float* prev_predictive = (const float*)d_in[2];
    const int*   seg_pre         = (const int*)d_in[3];
    const float* seg_perm        = (const float*)d_in[4];
    float* out = (float*)d_out;

    unsigned int*  ws_mask  = (unsigned int*)d_ws;
    unsigned char* ws_flags = (unsigned char*)d_ws + COLS * sizeof(unsigned int);

    tm_active_kernel<<<NCELLS / 256, 256, 0, stream>>>(
        active_columns, prev_predictive, out, ws_mask, ws_flags);

    tm_predict_kernel<<<PREDICT_GRID, 256, 0, stream>>>(
        seg_pre, seg_perm, ws_mask, ws_flags,
        out + NCELLS, out + 2 * NCELLS);
}